// Round 1
// baseline (893.036 us; speedup 1.0000x reference)
//
#include <hip/hip_runtime.h>

// SynthesisBlock: style-modulated 3x3 conv, bf16 implicit-GEMM MFMA.
// d_ws layout: [0,16KB) style fp32[16][256]; [16KB,32KB) demod fp32[16][256];
// [32KB, 32KB+1.125MB) repacked bf16 weights Wp[kh][cc][m 256][kw 3][ci 32].
// Requires ws_size >= ~1.2 MiB.
//
// R1: merged the mt (out-channel-half) split -> one block = all 256 out ch,
// 8 waves / 512 threads. Halves content staging traffic. Added chunked XCD
// swizzle (adjacent h rows -> same XCD L2) and LDS-cached style/demod rows.

typedef __bf16 bf16;
typedef bf16 bf16x8 __attribute__((ext_vector_type(8)));
typedef bf16 bf16x4 __attribute__((ext_vector_type(4)));
typedef float f32x4 __attribute__((ext_vector_type(4)));

#define GLOBAL_AS __attribute__((address_space(1)))
#define LDS_AS __attribute__((address_space(3)))

// ---------------- prep: style[b][i] = latent[b]·aff_w[i]*sqrt(1/512) + aff_b[i]
__global__ __launch_bounds__(256) void style_k(const float* __restrict__ latent,
                                               const float* __restrict__ aff_w,
                                               const float* __restrict__ aff_b,
                                               float* __restrict__ style) {
  const int wid = blockIdx.x * 4 + (threadIdx.x >> 6);  // 0..4095
  const int lane = threadIdx.x & 63;
  const int b = wid >> 8, i = wid & 255;
  float acc = 0.f;
#pragma unroll
  for (int k = 0; k < 8; ++k) {
    const int l = lane + 64 * k;
    acc += latent[b * 512 + l] * aff_w[i * 512 + l];
  }
#pragma unroll
  for (int off = 32; off > 0; off >>= 1) acc += __shfl_xor(acc, off, 64);
  if (lane == 0) style[b * 256 + i] = acc * 0.04419417382415922f + aff_b[i];
}

// ---------------- prep: demod[b][o] = rsqrt(sum_i wsq[o][i]*style[b][i]^2 + 1e-8)
__global__ __launch_bounds__(256) void demod_k(const float* __restrict__ conv_w,
                                               const float* __restrict__ style,
                                               float* __restrict__ demod) {
  __shared__ float s_wsq[256];
  const int o = blockIdx.x, i = threadIdx.x;
  float wsq = 0.f;
#pragma unroll
  for (int t = 0; t < 9; ++t) {
    const float w = conv_w[(o * 256 + i) * 9 + t];
    wsq += w * w;
  }
  s_wsq[i] = wsq;
  __syncthreads();
  const int wv = threadIdx.x >> 6, lane = threadIdx.x & 63;
  for (int b = wv; b < 16; b += 4) {
    float p = 0.f;
#pragma unroll
    for (int k = 0; k < 4; ++k) {
      const int ii = lane + 64 * k;
      const float s = style[b * 256 + ii];
      p += s_wsq[ii] * s * s;
    }
#pragma unroll
    for (int off = 32; off > 0; off >>= 1) p += __shfl_xor(p, off, 64);
    if (lane == 0) demod[b * 256 + o] = rsqrtf(p + 1e-8f);
  }
}

// ---------------- prep: repack conv_w fp32[o][c][kh][kw] -> bf16 Wp[kh][cc][m][kw][ci]
__global__ __launch_bounds__(256) void wprep_k(const float* __restrict__ conv_w,
                                               bf16* __restrict__ wp) {
  const int idx = blockIdx.x * 256 + threadIdx.x;  // < 589824
  const int ci = idx & 31;
  const int t3 = idx >> 5;
  const int kw = t3 % 3;
  const int t4 = t3 / 3;
  const int m = t4 & 255;
  const int t5 = t4 >> 8;
  const int cc = t5 & 7, kh = t5 >> 3;
  const float v = conv_w[((m * 256 + cc * 32 + ci) * 3 + kh) * 3 + kw];
  wp[idx] = (bf16)v;
}

// ---------------- main conv: block tile M=256 (all out ch) x N=128 (one row), 8 waves
__global__ __launch_bounds__(512, 4) void conv_k(const float* __restrict__ content,
                                                 const float* __restrict__ noise,
                                                 const float* __restrict__ bias,
                                                 const float* __restrict__ nwp,
                                                 const float* __restrict__ style,
                                                 const float* __restrict__ demod,
                                                 const bf16* __restrict__ wp,
                                                 float* __restrict__ out) {
  // ldsA: [256 m][96 = kw*32+ci] bf16 (49152 B). ldsX: [130 x][40 (32 ci + pad)] bf16 (10400 B).
  // sStyle/sDemod: fp32[256] each (2048 B). Total 61600 B -> 2 blocks/CU.
  __shared__ __align__(16) char smem[49152 + 10400 + 2048];
  bf16* ldsA = (bf16*)smem;
  bf16* ldsX = (bf16*)(smem + 49152);
  float* sStyle = (float*)(smem + 49152 + 10400);
  float* sDemod = sStyle + 256;

  const int tid = threadIdx.x;
  const int lane = tid & 63, wv = tid >> 6;       // 8 waves
  // chunked XCD swizzle: hardware round-robins blockIdx%8 -> XCD; give each XCD
  // a contiguous range of (b,h) tiles so adjacent rows share L2. 2048 % 8 == 0.
  const int bid = blockIdx.x;
  const int sp = ((bid & 7) << 8) | (bid >> 3);   // 0..2047, bijective
  const int h = sp & 127, b = sp >> 7;
  const int g = lane >> 4, nl = lane & 15;
  const int m0 = (wv & 3) * 64;                   // 4 m-tiles -> M=256
  const int n0 = (wv >> 2) * 64;                  // 2 n-tiles -> N=128
  const int wS = tid & 127, qi = tid >> 7;        // staging: w column, quad group 0..3

  // cache style/demod rows for this image
  if (tid < 256) sStyle[tid] = style[b * 256 + tid];
  else sDemod[tid - 256] = demod[b * 256 + (tid - 256)];

  f32x4 acc[4][4];
  const f32x4 zero4 = {0.f, 0.f, 0.f, 0.f};
#pragma unroll
  for (int mb = 0; mb < 4; ++mb)
#pragma unroll
    for (int nb = 0; nb < 4; ++nb) acc[mb][nb] = zero4;

  const float* srcb = content + ((size_t)b * 256) * 16384;
  __syncthreads();  // sStyle ready

  for (int cc = 0; cc < 8; ++cc) {
    const float* stl = sStyle + cc * 32;
    for (int kh = 0; kh < 3; ++kh) {
      const int gh = h + kh - 1;
      if (gh < 0 || gh >= 128) continue;  // block-uniform: zero-pad rows contribute nothing
      // ---- stage A (weights) via async global->LDS, 48 KiB contiguous (all 256 m)
      {
        const bf16* seg = wp + ((size_t)((kh * 8 + cc) * 256)) * 96;
#pragma unroll
        for (int i = 0; i < 6; ++i) {
          const int u = wv * 384 + i * 64 + lane;  // 16B units, 0..3071
          __builtin_amdgcn_global_load_lds((const GLOBAL_AS void*)(seg + u * 8),
                                           (LDS_AS void*)(ldsA + u * 8), 16, 0, 0);
        }
      }
      // ---- stage X: one input row, 32 channels, modulated + bf16, transposed [x][ci]
      {
        const float* src = srcb + (size_t)(cc * 32) * 16384 + gh * 128 + wS;
#pragma unroll
        for (int jj = 0; jj < 2; ++jj) {
          const int q = qi + jj * 4;  // quad 0..7 = ci 4q..4q+3
          const float v0 = src[(q * 4 + 0) * 16384] * stl[q * 4 + 0];
          const float v1 = src[(q * 4 + 1) * 16384] * stl[q * 4 + 1];
          const float v2 = src[(q * 4 + 2) * 16384] * stl[q * 4 + 2];
          const float v3 = src[(q * 4 + 3) * 16384] * stl[q * 4 + 3];
          bf16x4 pk = {(bf16)v0, (bf16)v1, (bf16)v2, (bf16)v3};
          *(bf16x4*)(ldsX + (wS + 1) * 40 + q * 4) = pk;
        }
        if (tid < 16) {  // halo columns x=0 (w=-1) and x=129 (w=128) are image pad -> 0
          const int xh = (tid >> 3) ? 129 : 0;
          const int q = tid & 7;
          bf16x4 z = {(bf16)0.f, (bf16)0.f, (bf16)0.f, (bf16)0.f};
          *(bf16x4*)(ldsX + xh * 40 + q * 4) = z;
        }
      }
      __syncthreads();
      // ---- compute: 3 kw steps, each one K=32 MFMA step over the 32-channel chunk
#pragma unroll
      for (int kw = 0; kw < 3; ++kw) {
        bf16x8 af[4], xf[4];
#pragma unroll
        for (int mb = 0; mb < 4; ++mb)
          af[mb] = *(const bf16x8*)(ldsA + (m0 + mb * 16 + nl) * 96 + kw * 32 + g * 8);
#pragma unroll
        for (int nb = 0; nb < 4; ++nb)
          xf[nb] = *(const bf16x8*)(ldsX + (n0 + nb * 16 + nl + kw) * 40 + g * 8);
#pragma unroll
        for (int mb = 0; mb < 4; ++mb)
#pragma unroll
          for (int nb = 0; nb < 4; ++nb)
            acc[mb][nb] =
                __builtin_amdgcn_mfma_f32_16x16x32_bf16(af[mb], xf[nb], acc[mb][nb], 0, 0, 0);
      }
      __syncthreads();
    }
  }

  // ---- epilogue: demod, noise, bias, leaky_relu(0.2) * sqrt(2)
  const float nw = nwp[0];
#pragma unroll
  for (int mb = 0; mb < 4; ++mb) {
    const int o = m0 + mb * 16 + g * 4;  // D row = 4*(lane>>4)+reg
    const f32x4 dm = *(const f32x4*)(sDemod + o);
    const f32x4 bs = *(const f32x4*)(bias + o);
#pragma unroll
    for (int nb = 0; nb < 4; ++nb) {
      const int wo = n0 + nb * 16 + nl;  // D col = lane&15
      const float nz = nw * noise[b * 16384 + h * 128 + wo];
      float* op = out + ((size_t)(b * 256 + o)) * 16384 + h * 128 + wo;
#pragma unroll
      for (int r = 0; r < 4; ++r) {
        float y = acc[mb][nb][r] * dm[r] + nz + bs[r];
        y = (y > 0.f ? y : 0.2f * y) * 1.41421356237f;
        op[(size_t)r * 16384] = y;
      }
    }
  }
}

extern "C" void kernel_launch(void* const* d_in, const int* in_sizes, int n_in,
                              void* d_out, int out_size, void* d_ws, size_t ws_size,
                              hipStream_t stream) {
  const float* content = (const float*)d_in[0];
  const float* latent = (const float*)d_in[1];
  const float* noise = (const float*)d_in[2];
  const float* aff_w = (const float*)d_in[3];
  const float* aff_b = (const float*)d_in[4];
  const float* conv_w = (const float*)d_in[5];
  const float* bias = (const float*)d_in[6];
  const float* nw = (const float*)d_in[7];
  float* out = (float*)d_out;

  float* style = (float*)d_ws;                       // 16*256 fp32
  float* demod = style + 4096;                       // 16*256 fp32
  bf16* wp = (bf16*)((char*)d_ws + 32768);           // 589824 bf16

  style_k<<<1024, 256, 0, stream>>>(latent, aff_w, aff_b, style);
  demod_k<<<256, 256, 0, stream>>>(conv_w, style, demod);
  wprep_k<<<2304, 256, 0, stream>>>(conv_w, wp);
  conv_k<<<2048, 512, 0, stream>>>(content, noise, bias, nw, style, demod, wp, out);
}

// Round 2
// 685.563 us; speedup vs baseline: 1.3026x; 1.3026x over previous
//
#include <hip/hip_runtime.h>

// SynthesisBlock: style-modulated 3x3 conv, bf16 implicit-GEMM MFMA.
// d_ws layout: [0,16KB) style fp32[16][256]; [16KB,32KB) demod fp32[16][256];
// [32KB, 32KB+1.125MB) repacked bf16 weights Wp[kh][cc][m 256][kw 3][ci 32].
//
// R2: band blocks (2 output rows, N=256), 1024 threads / 16 waves, per-wave
// 64x64 tile (acc[4][4] -> 64 VGPR + 64 AGPR fits 4 waves/SIMD).
// A double-buffered (2x48KB) with prefetch-before-compute (T3 2-phase);
// X staged once per cc (4 rows incl halo), reused across all 3 kh taps.

typedef __bf16 bf16;
typedef bf16 bf16x8 __attribute__((ext_vector_type(8)));
typedef bf16 bf16x4 __attribute__((ext_vector_type(4)));
typedef float f32x4 __attribute__((ext_vector_type(4)));

#define GLOBAL_AS __attribute__((address_space(1)))
#define LDS_AS __attribute__((address_space(3)))

// ---------------- prep: style[b][i] = latent[b]·aff_w[i]*sqrt(1/512) + aff_b[i]
__global__ __launch_bounds__(256) void style_k(const float* __restrict__ latent,
                                               const float* __restrict__ aff_w,
                                               const float* __restrict__ aff_b,
                                               float* __restrict__ style) {
  const int wid = blockIdx.x * 4 + (threadIdx.x >> 6);  // 0..4095
  const int lane = threadIdx.x & 63;
  const int b = wid >> 8, i = wid & 255;
  float acc = 0.f;
#pragma unroll
  for (int k = 0; k < 8; ++k) {
    const int l = lane + 64 * k;
    acc += latent[b * 512 + l] * aff_w[i * 512 + l];
  }
#pragma unroll
  for (int off = 32; off > 0; off >>= 1) acc += __shfl_xor(acc, off, 64);
  if (lane == 0) style[b * 256 + i] = acc * 0.04419417382415922f + aff_b[i];
}

// ---------------- prep: demod[b][o] = rsqrt(sum_i wsq[o][i]*style[b][i]^2 + 1e-8)
__global__ __launch_bounds__(256) void demod_k(const float* __restrict__ conv_w,
                                               const float* __restrict__ style,
                                               float* __restrict__ demod) {
  __shared__ float s_wsq[256];
  const int o = blockIdx.x, i = threadIdx.x;
  float wsq = 0.f;
#pragma unroll
  for (int t = 0; t < 9; ++t) {
    const float w = conv_w[(o * 256 + i) * 9 + t];
    wsq += w * w;
  }
  s_wsq[i] = wsq;
  __syncthreads();
  const int wv = threadIdx.x >> 6, lane = threadIdx.x & 63;
  for (int b = wv; b < 16; b += 4) {
    float p = 0.f;
#pragma unroll
    for (int k = 0; k < 4; ++k) {
      const int ii = lane + 64 * k;
      const float s = style[b * 256 + ii];
      p += s_wsq[ii] * s * s;
    }
#pragma unroll
    for (int off = 32; off > 0; off >>= 1) p += __shfl_xor(p, off, 64);
    if (lane == 0) demod[b * 256 + o] = rsqrtf(p + 1e-8f);
  }
}

// ---------------- prep: repack conv_w fp32[o][c][kh][kw] -> bf16 Wp[kh][cc][m][kw][ci]
__global__ __launch_bounds__(256) void wprep_k(const float* __restrict__ conv_w,
                                               bf16* __restrict__ wp) {
  const int idx = blockIdx.x * 256 + threadIdx.x;  // < 589824
  const int ci = idx & 31;
  const int t3 = idx >> 5;
  const int kw = t3 % 3;
  const int t4 = t3 / 3;
  const int m = t4 & 255;
  const int t5 = t4 >> 8;
  const int cc = t5 & 7, kh = t5 >> 3;
  const float v = conv_w[((m * 256 + cc * 32 + ci) * 3 + kh) * 3 + kw];
  wp[idx] = (bf16)v;
}

// ---------------- main conv: block = M=256 out-ch x N=256 (2 rows), 16 waves
__global__ __launch_bounds__(1024, 4) void conv_k(const float* __restrict__ content,
                                                  const float* __restrict__ noise,
                                                  const float* __restrict__ bias,
                                                  const float* __restrict__ nwp,
                                                  const float* __restrict__ style,
                                                  const float* __restrict__ demod,
                                                  const bf16* __restrict__ wp,
                                                  float* __restrict__ out) {
  // ldsA: double-buffer [2][256 m][96 = kw*32+ci] bf16 (98304 B).
  // ldsX: [4 rows][130 x][40 (32 ci + pad)] bf16 (41600 B). Total 139904 B.
  __shared__ __align__(16) char smem[98304 + 41600];
  bf16* ldsA = (bf16*)smem;             // two 24576-bf16 buffers
  bf16* ldsX = (bf16*)(smem + 98304);

  const int tid = threadIdx.x;
  const int lane = tid & 63, wv = tid >> 6;  // 16 waves
  // chunked XCD swizzle: 1024 blocks, 8 XCDs -> 128 consecutive band-tiles/XCD
  const int bid = blockIdx.x;
  const int sp = ((bid & 7) << 7) | (bid >> 3);  // bijective, 1024 % 8 == 0
  const int band = sp & 63, b = sp >> 6;
  const int h0 = band * 2;                       // output rows h0, h0+1
  const int g = lane >> 4, nl = lane & 15;
  const int m0 = (wv & 3) * 64;                  // 4 m-tiles -> M=256
  const int nseg = wv >> 2;                      // 0..3
  const int rr = nseg >> 1;                      // output row within band (0/1)
  const int x0 = (nseg & 1) * 64;                // 64-px column half
  const int wS = tid & 127, grp = tid >> 7;      // X staging: column, ci-quad

  f32x4 acc[4][4];
  const f32x4 zero4 = {0.f, 0.f, 0.f, 0.f};
#pragma unroll
  for (int mb = 0; mb < 4; ++mb)
#pragma unroll
    for (int nb = 0; nb < 4; ++nb) acc[mb][nb] = zero4;

  const float* srcb = content + ((size_t)b * 256) * 16384;

  // prologue: stage A(kh=0, cc=0) into buffer 0 (async; drained at first barrier)
  {
#pragma unroll
    for (int i = 0; i < 3; ++i) {
      const int u = tid + i * 1024;  // 16B units, 0..3071
      __builtin_amdgcn_global_load_lds((const GLOBAL_AS void*)(wp + u * 8),
                                       (LDS_AS void*)(ldsA + u * 8), 16, 0, 0);
    }
  }

  int cur = 0;
  for (int cc = 0; cc < 8; ++cc) {
    // ---- stage X once per cc: 4 rows (h0-1 .. h0+2), 32 ch, modulated bf16
    {
      const int c0 = cc * 32 + grp * 4;
      const float s0 = style[b * 256 + c0 + 0];
      const float s1 = style[b * 256 + c0 + 1];
      const float s2 = style[b * 256 + c0 + 2];
      const float s3 = style[b * 256 + c0 + 3];
#pragma unroll
      for (int r = 0; r < 4; ++r) {
        const int gh = h0 - 1 + r;
        bf16x4 pk = {(bf16)0.f, (bf16)0.f, (bf16)0.f, (bf16)0.f};
        if (gh >= 0 && gh < 128) {  // block-uniform branch
          const float* src = srcb + (size_t)c0 * 16384 + gh * 128 + wS;
          pk[0] = (bf16)(src[0] * s0);
          pk[1] = (bf16)(src[16384] * s1);
          pk[2] = (bf16)(src[2 * 16384] * s2);
          pk[3] = (bf16)(src[3 * 16384] * s3);
        }
        *(bf16x4*)(ldsX + (r * 130 + wS + 1) * 40 + grp * 4) = pk;
      }
      if (tid < 64) {  // halo columns x=0 (w=-1) and x=129 (w=128): image pad -> 0
        const int r = tid >> 4, xh = ((tid >> 3) & 1) ? 129 : 0, q = tid & 7;
        bf16x4 z = {(bf16)0.f, (bf16)0.f, (bf16)0.f, (bf16)0.f};
        *(bf16x4*)(ldsX + (r * 130 + xh) * 40 + q * 4) = z;
      }
    }
    __syncthreads();  // X visible (and drains A prefetch for this cc's kh=0)

    for (int kh = 0; kh < 3; ++kh) {
      // ---- prefetch next A tile into the other buffer (overlaps compute below)
      const int ncc = (kh == 2) ? cc + 1 : cc;
      const int nkh = (kh == 2) ? 0 : kh + 1;
      if (ncc < 8) {
        const bf16* seg = wp + (size_t)((nkh * 8 + ncc) * 256) * 96;
        bf16* dstA = ldsA + (cur ^ 1) * 24576;
#pragma unroll
        for (int i = 0; i < 3; ++i) {
          const int u = tid + i * 1024;
          __builtin_amdgcn_global_load_lds((const GLOBAL_AS void*)(seg + u * 8),
                                           (LDS_AS void*)(dstA + u * 8), 16, 0, 0);
        }
      }
      // ---- compute: 3 kw steps on current A buffer + X row (rr+kh)
      const bf16* Abuf = ldsA + cur * 24576;
      const int xrow = rr + kh;
#pragma unroll
      for (int kw = 0; kw < 3; ++kw) {
        bf16x8 af[4], xf[4];
#pragma unroll
        for (int mb = 0; mb < 4; ++mb)
          af[mb] = *(const bf16x8*)(Abuf + (m0 + mb * 16 + nl) * 96 + kw * 32 + g * 8);
#pragma unroll
        for (int nb = 0; nb < 4; ++nb)
          xf[nb] = *(const bf16x8*)(ldsX + (xrow * 130 + x0 + nb * 16 + nl + kw) * 40 + g * 8);
#pragma unroll
        for (int mb = 0; mb < 4; ++mb)
#pragma unroll
          for (int nb = 0; nb < 4; ++nb)
            acc[mb][nb] =
                __builtin_amdgcn_mfma_f32_16x16x32_bf16(af[mb], xf[nb], acc[mb][nb], 0, 0, 0);
      }
      cur ^= 1;
      __syncthreads();  // drains prefetch (after compute) + protects buffers
    }
  }

  // ---- epilogue: demod, noise, bias, leaky_relu(0.2) * sqrt(2)
  const float nw = nwp[0];
  const int hr = h0 + rr;
#pragma unroll
  for (int mb = 0; mb < 4; ++mb) {
    const int o = m0 + mb * 16 + g * 4;  // D row = 4*(lane>>4)+reg
    const f32x4 dm = *(const f32x4*)(demod + b * 256 + o);
    const f32x4 bs = *(const f32x4*)(bias + o);
#pragma unroll
    for (int nb = 0; nb < 4; ++nb) {
      const int x = x0 + nb * 16 + nl;  // D col = lane&15
      const float nz = nw * noise[b * 16384 + hr * 128 + x];
      float* op = out + ((size_t)(b * 256 + o)) * 16384 + hr * 128 + x;
#pragma unroll
      for (int r = 0; r < 4; ++r) {
        float y = acc[mb][nb][r] * dm[r] + nz + bs[r];
        y = (y > 0.f ? y : 0.2f * y) * 1.41421356237f;
        op[(size_t)r * 16384] = y;
      }
    }
  }
}

extern "C" void kernel_launch(void* const* d_in, const int* in_sizes, int n_in,
                              void* d_out, int out_size, void* d_ws, size_t ws_size,
                              hipStream_t stream) {
  const float* content = (const float*)d_in[0];
  const float* latent = (const float*)d_in[1];
  const float* noise = (const float*)d_in[2];
  const float* aff_w = (const float*)d_in[3];
  const float* aff_b = (const float*)d_in[4];
  const float* conv_w = (const float*)d_in[5];
  const float* bias = (const float*)d_in[6];
  const float* nw = (const float*)d_in[7];
  float* out = (float*)d_out;

  float* style = (float*)d_ws;                       // 16*256 fp32
  float* demod = style + 4096;                       // 16*256 fp32
  bf16* wp = (bf16*)((char*)d_ws + 32768);           // 589824 bf16

  style_k<<<1024, 256, 0, stream>>>(latent, aff_w, aff_b, style);
  demod_k<<<256, 256, 0, stream>>>(conv_w, style, demod);
  wprep_k<<<2304, 256, 0, stream>>>(conv_w, wp);
  conv_k<<<1024, 1024, 0, stream>>>(content, noise, bias, nw, style, demod, wp, out);
}